// Round 11
// baseline (442.517 us; speedup 1.0000x reference)
//
#include <hip/hip_runtime.h>
#include <hip/hip_bf16.h>

#define HIDDEN   2880
#define INTER    2880
#define NEXP     8
#define GUP_ROWS 5760
#define NPAIR    2048

#define NKT   45             // k-tiles of 64
#define BM    320
#define BN    160            // both gemms
#define TILE_B  40960        // per (tile,kt): 8 planes x 320 rows x 16B
#define PLANE_B 5120

#define MAXTILES 15
#define IMG_BYTES ((size_t)MAXTILES * NKT * TILE_B)   // ~27.6 MB

#define ABUF 40960           // LDS A buffer (one kt)
#define BBUF 40960           // LDS B buffer (160 cols x 256B f32)

using bf16x8 = __attribute__((ext_vector_type(8))) short;
using f32x4  = __attribute__((ext_vector_type(4))) float;

typedef const __attribute__((address_space(1))) unsigned GBuf;
typedef __attribute__((address_space(3))) unsigned LBuf;

__device__ __forceinline__ void gl2lds(const void* g, void* l) {
  __builtin_amdgcn_global_load_lds((GBuf*)g, (LBuf*)l, 16, 0, 0);
}
#define WAITVM(N) { asm volatile("s_waitcnt vmcnt(" #N ")" ::: "memory"); \
                    __builtin_amdgcn_sched_barrier(0); }
__device__ __forceinline__ void barrier() {
  __builtin_amdgcn_sched_barrier(0);
  __builtin_amdgcn_s_barrier();
  __builtin_amdgcn_sched_barrier(0);
}

__device__ __forceinline__ unsigned cvt2bf(float a, float b) {
  union { __hip_bfloat16 h; unsigned short s; } x, y;
  x.h = __float2bfloat16(a);
  y.h = __float2bfloat16(b);
  return (unsigned)x.s | ((unsigned)y.s << 16);
}
__device__ __forceinline__ bf16x8 cvt8(const float4& lo, const float4& hi) {
  union { bf16x8 v; unsigned u[4]; } r;
  r.u[0] = cvt2bf(lo.x, lo.y);
  r.u[1] = cvt2bf(lo.z, lo.w);
  r.u[2] = cvt2bf(hi.x, hi.y);
  r.u[3] = cvt2bf(hi.z, hi.w);
  return r.v;
}

// ---------------- routing ----------------
// meta: [0..7]=counts [8..15]=row offsets [16..23]=cursor [24..31]=tile base
__global__ void route_count(const int* __restrict__ eidx, int* __restrict__ meta) {
  __shared__ int cnt[NEXP];
  int t = threadIdx.x;
  if (t < NEXP) cnt[t] = 0;
  __syncthreads();
  for (int a = t; a < NPAIR; a += 256) atomicAdd(&cnt[eidx[a]], 1);
  __syncthreads();
  if (t == 0) {
    int off = 0, toff = 0;
    for (int e = 0; e < NEXP; ++e) {
      meta[e] = cnt[e];
      meta[8 + e] = off;
      meta[16 + e] = off;
      meta[24 + e] = toff;
      off += cnt[e];
      toff += (cnt[e] + BM - 1) / BM;
    }
  }
}

__global__ void route_scatter(const int* __restrict__ eidx, int* __restrict__ meta,
                              int* __restrict__ list) {
  int a = blockIdx.x * 256 + threadIdx.x;
  int e = eidx[a];
  int pos = atomicAdd(&meta[16 + e], 1);
  list[pos] = a;
}

// ---------------- gather A rows -> bf16 tiled fragment image ----------------
// layout: [tile][kt(45)][plane p 0..7][row 0..319][16B],  k = kt*64 + p*8 + j
__global__ void gather_a(const float* __restrict__ t, const int* __restrict__ eidx,
                         const int* __restrict__ meta, const int* __restrict__ list,
                         char* __restrict__ atile) {
  const int i = blockIdx.x;
  const int a = list[i];
  const int e = eidx[a];
  const int r = i - meta[8 + e];
  const int tile = meta[24 + e] + r / BM;
  const int row = r % BM;
  const float* src = t + (size_t)(a >> 2) * HIDDEN;
  for (int ch = threadIdx.x; ch < HIDDEN / 8; ch += 256) {
    int kt = ch >> 3, p = ch & 7;
    const float4* s = (const float4*)(src + ch * 8);
    float4 v0 = s[0], v1 = s[1];
    uint4 w;
    w.x = cvt2bf(v0.x, v0.y); w.y = cvt2bf(v0.z, v0.w);
    w.z = cvt2bf(v1.x, v1.y); w.w = cvt2bf(v1.z, v1.w);
    *(uint4*)(atile + (size_t)(tile * NKT + kt) * TILE_B + p * PLANE_B + row * 16) = w;
  }
}

// ---------------- GEMM core: 8 waves (4 wm x 2 wn), tile 320x160, BK=64 ----------------
// LDS: A dbuf 2x40KB + B dbuf 2x40KB = 160KB (1 block/CU).
// Staging per iter per wave: V A-chunks (V=ceil(rows/64)<=5) + 5 B-chunks -> vmcnt(V+5).
template<int NCOLS_TOT, bool SWIGLU>
__global__ __launch_bounds__(512, 2)
void gemm_core(const char* __restrict__ aimg,
               const float* __restrict__ wgt,
               const float* __restrict__ wbias,
               const int* __restrict__ meta,
               const int* __restrict__ list,
               char* __restrict__ uimg,
               float* __restrict__ out)
{
  const int e = blockIdx.x, nt = blockIdx.y, mt = blockIdx.z;
  const int n_e = meta[e];
  const int m0 = mt * BM;
  if (m0 >= n_e) return;
  const int tile = meta[24 + e] + mt;
  int rows = n_e - m0; if (rows > BM) rows = BM;
  const int V = (rows + 63) >> 6;   // 1..5, block-uniform

  __shared__ __align__(16) char lds[2 * ABUF + 2 * BBUF];   // 160 KB
  char* ldsB = lds + 2 * ABUF;

  const int tid = threadIdx.x, lane = tid & 63, wid = tid >> 6;
  const int wm = wid >> 1, wn = wid & 1;
  const int kq = lane >> 4, l15 = lane & 15;

  const char* aSrcBase = aimg + (size_t)tile * NKT * TILE_B;
  // A: wave w owns plane w, row-groups j=0..4 (1KB each). V-skip on j.
  const char* srcA[5];
  int dstA[5];
  #pragma unroll
  for (int j = 0; j < 5; ++j) {
    srcA[j] = aSrcBase + wid * PLANE_B + j * 1024 + lane * 16;
    dstA[j] = wid * PLANE_B + j * 1024;
  }
  // B: 40 chunks of 1KB (4 cols x 256B), 5 per wave; bank-swizzle in SOURCE addr
  const char* srcB[5];
  int dstB[5];
  #pragma unroll
  for (int j = 0; j < 5; ++j) {
    int cb = wid * 5 + j;
    int col = nt * BN + cb * 4 + (lane >> 4);
    int s16 = lane & 15;
    int swz = (((s16 >> 1) ^ (col & 7)) << 5) | ((s16 & 1) << 4);
    srcB[j] = (const char*)wgt + ((size_t)(e * NCOLS_TOT + col) * HIDDEN) * 4 + swz;
    dstB[j] = cb * 1024;
  }

  auto STAGE = [&](int kt, int buf) {
    #pragma unroll
    for (int j = 0; j < 5; ++j)
      if (j < V)
        gl2lds(srcA[j] + (size_t)kt * TILE_B, lds + buf * ABUF + dstA[j]);
    #pragma unroll
    for (int j = 0; j < 5; ++j)
      gl2lds(srcB[j] + (size_t)kt * 256, ldsB + buf * BBUF + dstB[j]);
  };

  f32x4 acc[5][5];
  #pragma unroll
  for (int fm = 0; fm < 5; ++fm)
    #pragma unroll
    for (int fn = 0; fn < 5; ++fn)
      acc[fm][fn] = f32x4{0.f, 0.f, 0.f, 0.f};

  auto COMP = [&](int buf) {
    const char* aT = lds + buf * ABUF;
    const char* bT = ldsB + buf * BBUF;
    #pragma unroll
    for (int s = 0; s < 2; ++s) {
      const char* aB = aT + (s * 4 + kq) * PLANE_B + (wm * 80 + l15) * 16;
      bf16x8 af[5], bf[5];
      #pragma unroll
      for (int fm = 0; fm < 5; ++fm) af[fm] = *(const bf16x8*)(aB + fm * 256);
      #pragma unroll
      for (int fn = 0; fn < 5; ++fn) {
        int col = wn * 80 + fn * 16 + l15;
        int slot = ((s * 4 + kq) ^ (col & 7)) << 5;
        const char* cp = bT + col * 256 + slot;
        float4 lo = *(const float4*)cp;
        float4 hi = *(const float4*)(cp + 16);
        bf[fn] = cvt8(lo, hi);
      }
      #pragma unroll
      for (int fm = 0; fm < 5; ++fm)
        #pragma unroll
        for (int fn = 0; fn < 5; ++fn)
          acc[fm][fn] = __builtin_amdgcn_mfma_f32_16x16x32_bf16(af[fm], bf[fn], acc[fm][fn], 0, 0, 0);
    }
  };

  STAGE(0, 0);
  for (int kt = 0; kt < NKT; ++kt) {
    if (kt + 1 < NKT) {
      STAGE(kt + 1, (kt + 1) & 1);
      if      (V == 5) WAITVM(10)
      else if (V == 4) WAITVM(9)
      else if (V == 3) WAITVM(8)
      else if (V == 2) WAITVM(7)
      else             WAITVM(6)
    } else WAITVM(0)
    barrier();
    COMP(kt & 1);
    barrier();
  }

  if (SWIGLU) {
    #pragma unroll
    for (int fm = 0; fm < 5; ++fm) {
      #pragma unroll
      for (int fn = 0; fn < 5; ++fn) {
        const int colg = nt * BN + wn * 80 + fn * 16 + l15;
        const float bias = wbias[e * NCOLS_TOT + colg];
        #pragma unroll
        for (int j = 0; j < 4; ++j) {
          float h = acc[fm][fn][j] + bias;
          float other = __shfl_xor(h, 1, 64);
          int rowin = wm * 80 + fm * 16 + kq * 4 + j;
          if (!(lane & 1) && rowin < rows) {
            float xg = fminf(h, 7.0f);
            float xl = fminf(fmaxf(other, -7.0f), 7.0f);
            float og = xg / (1.0f + __expf(-1.702f * xg));
            float uv = og * (xl + 1.0f);
            int uc = colg >> 1;                      // 0..2879
            int kt2 = uc >> 6, p2 = (uc >> 3) & 7;
            *(__hip_bfloat16*)(uimg + (size_t)(tile * NKT + kt2) * TILE_B +
                p2 * PLANE_B + rowin * 16 + (uc & 7) * 2) = __float2bfloat16(uv);
          }
        }
      }
    }
  } else {
    const int base = meta[8 + e];
    #pragma unroll
    for (int fm = 0; fm < 5; ++fm) {
      #pragma unroll
      for (int j = 0; j < 4; ++j) {
        int rin = wm * 80 + fm * 16 + kq * 4 + j;
        int aidx = (rin < rows) ? list[base + m0 + rin] : -1;
        #pragma unroll
        for (int fn = 0; fn < 5; ++fn) {
          int col = nt * BN + wn * 80 + fn * 16 + l15;
          if (aidx >= 0)
            out[(size_t)aidx * HIDDEN + col] = acc[fm][fn][j] + wbias[e * NCOLS_TOT + col];
        }
      }
    }
  }
}

extern "C" void kernel_launch(void* const* d_in, const int* in_sizes, int n_in,
                              void* d_out, int out_size, void* d_ws, size_t ws_size,
                              hipStream_t stream) {
  const float* t     = (const float*)d_in[0];
  const int*   eidx  = (const int*)d_in[1];
  const float* gup   = (const float*)d_in[2];
  const float* gub   = (const float*)d_in[3];
  const float* dwn   = (const float*)d_in[4];
  const float* dbias = (const float*)d_in[5];
  float* out = (float*)d_out;

  char* ws = (char*)d_ws;
  char* atile = ws;
  char* utile = ws + IMG_BYTES;
  int* meta = (int*)(ws + 2 * IMG_BYTES);
  int* list = meta + 32;

  route_count<<<1, 256, 0, stream>>>(eidx, meta);
  route_scatter<<<NPAIR / 256, 256, 0, stream>>>(eidx, meta, list);
  gather_a<<<NPAIR, 256, 0, stream>>>(t, eidx, meta, list, atile);

  dim3 g1(NEXP, GUP_ROWS / BN, 2);   // 8 x 36 x 2 (mt=1 safety tier, normally exits)
  gemm_core<GUP_ROWS, true><<<g1, 512, 0, stream>>>(atile, gup, gub, meta, list, utile, out);

  dim3 g2(NEXP, HIDDEN / BN, 2);     // 8 x 18 x 2
  gemm_core<HIDDEN, false><<<g2, 512, 0, stream>>>(utile, dwn, dbias, meta, list, nullptr, out);
}

// Round 12
// 402.816 us; speedup vs baseline: 1.0986x; 1.0986x over previous
//
#include <hip/hip_runtime.h>
#include <hip/hip_bf16.h>

#define HIDDEN   2880
#define INTER    2880
#define NEXP     8
#define GUP_ROWS 5760
#define NPAIR    2048

#define NKT   90             // k-tiles of 32
#define BM    320
#define BN    96             // both gemms
#define ATILE 20480          // A image per (tile,kt): 4 kq-planes x 320 rows x 16B
#define APLANE 5120
#define BUFSZ  32768         // per-buffer: A 20480 + B 12288
#define NBUF   5             // 5 x 32KB = 160KB LDS, depth-4 pipeline

#define MAXTILES 14
#define IMG_BYTES ((size_t)MAXTILES * NKT * ATILE)   // ~25.8 MB

using bf16x8 = __attribute__((ext_vector_type(8))) short;
using f32x4  = __attribute__((ext_vector_type(4))) float;

typedef const __attribute__((address_space(1))) unsigned GBuf;
typedef __attribute__((address_space(3))) unsigned LBuf;

__device__ __forceinline__ void gl2lds(const void* g, void* l) {
  __builtin_amdgcn_global_load_lds((GBuf*)g, (LBuf*)l, 16, 0, 0);
}
#define WAITVM(N) { asm volatile("s_waitcnt vmcnt(" #N ")" ::: "memory"); \
                    __builtin_amdgcn_sched_barrier(0); }
__device__ __forceinline__ void barrier() {
  __builtin_amdgcn_sched_barrier(0);
  __builtin_amdgcn_s_barrier();
  __builtin_amdgcn_sched_barrier(0);
}

__device__ __forceinline__ unsigned cvt2bf(float a, float b) {
  union { __hip_bfloat16 h; unsigned short s; } x, y;
  x.h = __float2bfloat16(a);
  y.h = __float2bfloat16(b);
  return (unsigned)x.s | ((unsigned)y.s << 16);
}
__device__ __forceinline__ bf16x8 cvt8(const float4& lo, const float4& hi) {
  union { bf16x8 v; unsigned u[4]; } r;
  r.u[0] = cvt2bf(lo.x, lo.y);
  r.u[1] = cvt2bf(lo.z, lo.w);
  r.u[2] = cvt2bf(hi.x, hi.y);
  r.u[3] = cvt2bf(hi.z, hi.w);
  return r.v;
}

// ---------------- routing ----------------
// meta: [0..7]=counts [8..15]=row offsets [16..23]=cursor [24..31]=tile base
__global__ void route_count(const int* __restrict__ eidx, int* __restrict__ meta) {
  __shared__ int cnt[NEXP];
  int t = threadIdx.x;
  if (t < NEXP) cnt[t] = 0;
  __syncthreads();
  for (int a = t; a < NPAIR; a += 256) atomicAdd(&cnt[eidx[a]], 1);
  __syncthreads();
  if (t == 0) {
    int off = 0, toff = 0;
    for (int e = 0; e < NEXP; ++e) {
      meta[e] = cnt[e];
      meta[8 + e] = off;
      meta[16 + e] = off;
      meta[24 + e] = toff;
      off += cnt[e];
      toff += (cnt[e] + BM - 1) / BM;
    }
  }
}

__global__ void route_scatter(const int* __restrict__ eidx, int* __restrict__ meta,
                              int* __restrict__ list) {
  int a = blockIdx.x * 256 + threadIdx.x;
  int e = eidx[a];
  int pos = atomicAdd(&meta[16 + e], 1);
  list[pos] = a;
}

// ---------------- gather A rows -> bf16 tiled fragment image ----------------
// layout: [tile][kt 0..89][kq 0..3][row 0..319][16B],  k = kt*32 + kq*8 + j
__global__ void gather_a(const float* __restrict__ t, const int* __restrict__ eidx,
                         const int* __restrict__ meta, const int* __restrict__ list,
                         char* __restrict__ atile) {
  const int i = blockIdx.x;
  const int a = list[i];
  const int e = eidx[a];
  const int r = i - meta[8 + e];
  const int tile = meta[24 + e] + r / BM;
  const int row = r % BM;
  const float* src = t + (size_t)(a >> 2) * HIDDEN;
  for (int ch = threadIdx.x; ch < HIDDEN / 8; ch += 256) {
    int kt = ch >> 2, kq = ch & 3;
    const float4* s = (const float4*)(src + ch * 8);
    float4 v0 = s[0], v1 = s[1];
    uint4 w;
    w.x = cvt2bf(v0.x, v0.y); w.y = cvt2bf(v0.z, v0.w);
    w.z = cvt2bf(v1.x, v1.y); w.w = cvt2bf(v1.z, v1.w);
    *(uint4*)(atile + (size_t)(tile * NKT + kt) * ATILE + kq * APLANE + row * 16) = w;
  }
}

// ---------------- GEMM core: 8 waves (4 wm x 2 wn), tile 320x96, BK=32, depth-4 ----------------
// 32 chunks/iter (20 A-image + 12 B-f32), 4 gl2lds per wave -> WAITVM(12) = 3 iters in flight.
template<int NCOLS_TOT, bool SWIGLU>
__global__ __launch_bounds__(512, 2)
void gemm_core(const char* __restrict__ aimg,
               const float* __restrict__ wgt,
               const float* __restrict__ wbias,
               const int* __restrict__ meta,
               const int* __restrict__ list,
               char* __restrict__ uimg,
               float* __restrict__ out)
{
  const int e = blockIdx.x, nt = blockIdx.y, mt = blockIdx.z;
  const int n_e = meta[e];
  const int m0 = mt * BM;
  if (m0 >= n_e) return;
  const int tile = meta[24 + e] + mt;
  int rows = n_e - m0; if (rows > BM) rows = BM;

  __shared__ __align__(16) char lds[NBUF * BUFSZ];   // 160 KB exactly

  const int tid = threadIdx.x, lane = tid & 63, wid = tid >> 6;
  const int wm = wid >> 1, wn = wid & 1;
  const int kq = lane >> 4, l15 = lane & 15;

  const char* aSrc = aimg + (size_t)tile * NKT * ATILE;

  // 32 chunks of 1KB: c<20 -> A image (linear), else B (cb=c-20, 8 cols x 128B)
  const char* srcP[4]; int dstOff[4]; int strd[4];
  #pragma unroll
  for (int j = 0; j < 4; ++j) {
    int c = wid * 4 + j;
    if (c < 20) {
      srcP[j] = aSrc + c * 1024 + lane * 16;
      strd[j] = ATILE;
      dstOff[j] = c * 1024;
    } else {
      int cb = c - 20;
      int col = nt * BN + cb * 8 + (lane >> 3);
      int g = (lane & 7) >> 1, h = lane & 1;
      srcP[j] = (const char*)wgt + (size_t)(e * NCOLS_TOT + col) * (HIDDEN * 4)
                + (((g ^ (col & 3)) << 5) | (h << 4));
      strd[j] = 128;
      dstOff[j] = 20480 + cb * 1024;
    }
  }

  auto STAGE = [&](int kt, int b) {
    char* dst = lds + b * BUFSZ;
    #pragma unroll
    for (int j = 0; j < 4; ++j)
      gl2lds(srcP[j] + (size_t)kt * strd[j], dst + dstOff[j]);
  };

  f32x4 acc[5][3];
  #pragma unroll
  for (int fm = 0; fm < 5; ++fm)
    #pragma unroll
    for (int fn = 0; fn < 3; ++fn)
      acc[fm][fn] = f32x4{0.f, 0.f, 0.f, 0.f};

  auto COMP = [&](int b) {
    const char* base = lds + b * BUFSZ;
    const char* aB = base + kq * APLANE + (wm * 80 + l15) * 16;
    bf16x8 af[5], bf[3];
    #pragma unroll
    for (int fm = 0; fm < 5; ++fm) af[fm] = *(const bf16x8*)(aB + fm * 256);
    #pragma unroll
    for (int fn = 0; fn < 3; ++fn) {
      int col = wn * 48 + fn * 16 + l15;
      const char* cp = base + 20480 + col * 128 + ((kq ^ (col & 3)) << 5);
      float4 lo = *(const float4*)cp;
      float4 hi = *(const float4*)(cp + 16);
      bf[fn] = cvt8(lo, hi);
    }
    #pragma unroll
    for (int fm = 0; fm < 5; ++fm)
      #pragma unroll
      for (int fn = 0; fn < 3; ++fn)
        acc[fm][fn] = __builtin_amdgcn_mfma_f32_16x16x32_bf16(af[fm], bf[fn], acc[fm][fn], 0, 0, 0);
  };

  // prologue: 4 tiles in flight
  STAGE(0, 0); STAGE(1, 1); STAGE(2, 2); STAGE(3, 3);
  int b = 0, sb = 4;
  for (int kt = 0; kt < NKT - 4; ++kt) {    // kt = 0..85, stages 4..89
    WAITVM(12);
    barrier();
    COMP(b);
    barrier();
    STAGE(kt + 4, sb);
    b  = (b  == 4) ? 0 : b  + 1;
    sb = (sb == 4) ? 0 : sb + 1;
  }
  // peeled tail: kt = 86..89
  WAITVM(12); barrier(); COMP(b); barrier(); b = (b == 4) ? 0 : b + 1;
  WAITVM(8);  barrier(); COMP(b); barrier(); b = (b == 4) ? 0 : b + 1;
  WAITVM(4);  barrier(); COMP(b); barrier(); b = (b == 4) ? 0 : b + 1;
  WAITVM(0);  barrier(); COMP(b);

  if (SWIGLU) {
    // +bias, swiglu (even col = glu, odd = lin), write u into uimg image
    #pragma unroll
    for (int fm = 0; fm < 5; ++fm) {
      #pragma unroll
      for (int fn = 0; fn < 3; ++fn) {
        const int colg = nt * BN + wn * 48 + fn * 16 + l15;
        const float bias = wbias[e * NCOLS_TOT + colg];
        #pragma unroll
        for (int j = 0; j < 4; ++j) {
          float h = acc[fm][fn][j] + bias;
          float other = __shfl_xor(h, 1, 64);
          int rowin = wm * 80 + fm * 16 + kq * 4 + j;
          if (!(lane & 1) && rowin < rows) {
            float xg = fminf(h, 7.0f);
            float xl = fminf(fmaxf(other, -7.0f), 7.0f);
            float og = xg / (1.0f + __expf(-1.702f * xg));
            float uv = og * (xl + 1.0f);
            int uc = colg >> 1;                      // 0..2879
            int kt2 = uc >> 5, kq2 = (uc >> 3) & 3;
            *(__hip_bfloat16*)(uimg + (size_t)(tile * NKT + kt2) * ATILE +
                kq2 * APLANE + rowin * 16 + (uc & 7) * 2) = __float2bfloat16(uv);
          }
        }
      }
    }
  } else {
    const int base = meta[8 + e];
    #pragma unroll
    for (int fm = 0; fm < 5; ++fm) {
      #pragma unroll
      for (int j = 0; j < 4; ++j) {
        int rin = wm * 80 + fm * 16 + kq * 4 + j;
        int aidx = (rin < rows) ? list[base + m0 + rin] : -1;
        #pragma unroll
        for (int fn = 0; fn < 3; ++fn) {
          int col = nt * BN + wn * 48 + fn * 16 + l15;
          if (aidx >= 0)
            out[(size_t)aidx * HIDDEN + col] = acc[fm][fn][j] + wbias[e * NCOLS_TOT + col];
        }
      }
    }
  }
}

extern "C" void kernel_launch(void* const* d_in, const int* in_sizes, int n_in,
                              void* d_out, int out_size, void* d_ws, size_t ws_size,
                              hipStream_t stream) {
  const float* t     = (const float*)d_in[0];
  const int*   eidx  = (const int*)d_in[1];
  const float* gup   = (const float*)d_in[2];
  const float* gub   = (const float*)d_in[3];
  const float* dwn   = (const float*)d_in[4];
  const float* dbias = (const float*)d_in[5];
  float* out = (float*)d_out;

  char* ws = (char*)d_ws;
  char* atile = ws;
  char* utile = ws + IMG_BYTES;
  int* meta = (int*)(ws + 2 * IMG_BYTES);
  int* list = meta + 32;

  route_count<<<1, 256, 0, stream>>>(eidx, meta);
  route_scatter<<<NPAIR / 256, 256, 0, stream>>>(eidx, meta, list);
  gather_a<<<NPAIR, 256, 0, stream>>>(t, eidx, meta, list, atile);

  dim3 g1(NEXP, GUP_ROWS / BN, 2);   // 8 x 60 x 2 (mt=1 safety tier, normally exits)
  gemm_core<GUP_ROWS, true><<<g1, 512, 0, stream>>>(atile, gup, gub, meta, list, utile, out);

  dim3 g2(NEXP, HIDDEN / BN, 2);     // 8 x 30 x 2
  gemm_core<HIDDEN, false><<<g2, 512, 0, stream>>>(utile, dwn, dbias, meta, list, nullptr, out);
}

// Round 13
// 397.522 us; speedup vs baseline: 1.1132x; 1.0133x over previous
//
#include <hip/hip_runtime.h>
#include <hip/hip_bf16.h>

#define HIDDEN   2880
#define INTER    2880
#define NEXP     8
#define GUP_ROWS 5760
#define NPAIR    2048

#define NKT   45             // k-tiles of 64
#define BM    320
#define TILE_B  40960        // image per (tile,kt): 8 planes x 320 rows x 16B
#define PLANE_B 5120
#define ABUF    40960

#define MAXTILES 15
#define IMG_BYTES ((size_t)MAXTILES * NKT * TILE_B)

using bf16x8 = __attribute__((ext_vector_type(8))) short;
using f32x4  = __attribute__((ext_vector_type(4))) float;

typedef const __attribute__((address_space(1))) unsigned GBuf;
typedef __attribute__((address_space(3))) unsigned LBuf;

__device__ __forceinline__ void gl2lds(const void* g, void* l) {
  __builtin_amdgcn_global_load_lds((GBuf*)g, (LBuf*)l, 16, 0, 0);
}
#define WAITVM(N) { asm volatile("s_waitcnt vmcnt(" #N ")" ::: "memory"); \
                    __builtin_amdgcn_sched_barrier(0); }
__device__ __forceinline__ void barrier() {
  __builtin_amdgcn_sched_barrier(0);
  __builtin_amdgcn_s_barrier();
  __builtin_amdgcn_sched_barrier(0);
}

__device__ __forceinline__ unsigned cvt2bf(float a, float b) {
  union { __hip_bfloat16 h; unsigned short s; } x, y;
  x.h = __float2bfloat16(a);
  y.h = __float2bfloat16(b);
  return (unsigned)x.s | ((unsigned)y.s << 16);
}
__device__ __forceinline__ bf16x8 cvt8(const float4& lo, const float4& hi) {
  union { bf16x8 v; unsigned u[4]; } r;
  r.u[0] = cvt2bf(lo.x, lo.y);
  r.u[1] = cvt2bf(lo.z, lo.w);
  r.u[2] = cvt2bf(hi.x, hi.y);
  r.u[3] = cvt2bf(hi.z, hi.w);
  return r.v;
}

// ---------------- routing ----------------
__global__ void route_count(const int* __restrict__ eidx, int* __restrict__ meta) {
  __shared__ int cnt[NEXP];
  int t = threadIdx.x;
  if (t < NEXP) cnt[t] = 0;
  __syncthreads();
  for (int a = t; a < NPAIR; a += 256) atomicAdd(&cnt[eidx[a]], 1);
  __syncthreads();
  if (t == 0) {
    int off = 0, toff = 0;
    for (int e = 0; e < NEXP; ++e) {
      meta[e] = cnt[e];
      meta[8 + e] = off;
      meta[16 + e] = off;
      meta[24 + e] = toff;
      off += cnt[e];
      toff += (cnt[e] + BM - 1) / BM;
    }
  }
}

__global__ void route_scatter(const int* __restrict__ eidx, int* __restrict__ meta,
                              int* __restrict__ list) {
  int a = blockIdx.x * 256 + threadIdx.x;
  int e = eidx[a];
  int pos = atomicAdd(&meta[16 + e], 1);
  list[pos] = a;
}

// ---------------- gather A rows -> bf16 tiled fragment image ----------------
// layout: [tile][kt(45)][plane p 0..7][row 0..319][16B],  k = kt*64 + p*8 + j
__global__ void gather_a(const float* __restrict__ t, const int* __restrict__ eidx,
                         const int* __restrict__ meta, const int* __restrict__ list,
                         char* __restrict__ atile) {
  const int i = blockIdx.x;
  const int a = list[i];
  const int e = eidx[a];
  const int r = i - meta[8 + e];
  const int tile = meta[24 + e] + r / BM;
  const int row = r % BM;
  const float* src = t + (size_t)(a >> 2) * HIDDEN;
  for (int ch = threadIdx.x; ch < HIDDEN / 8; ch += 256) {
    int kt = ch >> 3, p = ch & 7;
    const float4* s = (const float4*)(src + ch * 8);
    float4 v0 = s[0], v1 = s[1];
    uint4 w;
    w.x = cvt2bf(v0.x, v0.y); w.y = cvt2bf(v0.z, v0.w);
    w.z = cvt2bf(v1.x, v1.y); w.w = cvt2bf(v1.z, v1.w);
    *(uint4*)(atile + (size_t)(tile * NKT + kt) * TILE_B + p * PLANE_B + row * 16) = w;
  }
}

// ---------------- GEMM core: 8 waves (4 wm x 2 wn), tile 320xBN_, BK=64, depth-1 ----------------
// BN_=160: LDS 160KB, 10 gl2lds/wave/iter -> WAITVM(10). BN_=96: 128KB, 8 -> WAITVM(8).
template<int BN_, int NCOLS_TOT, bool SWIGLU>
__global__ __launch_bounds__(512, 1)
void gemm_core(const char* __restrict__ aimg,
               const float* __restrict__ wgt,
               const float* __restrict__ wbias,
               const int* __restrict__ meta,
               const int* __restrict__ list,
               char* __restrict__ uimg,
               float* __restrict__ out)
{
  constexpr int FN = BN_ / 32;          // 5 or 3
  constexpr int BCH = BN_ / 4;          // B chunks per block (40 or 24)
  constexpr int BBUF = BN_ * 256;       // B bytes per buffer

  const int e = blockIdx.x, nt = blockIdx.y, mt = blockIdx.z;
  const int n_e = meta[e];
  const int m0 = mt * BM;
  if (m0 >= n_e) return;
  const int tile = meta[24 + e] + mt;
  int rows = n_e - m0; if (rows > BM) rows = BM;

  __shared__ __align__(16) char lds[2 * ABUF + 2 * BBUF];
  char* ldsB = lds + 2 * ABUF;

  const int tid = threadIdx.x, lane = tid & 63, wid = tid >> 6;
  const int wm = wid >> 1, wn = wid & 1;
  const int kq = lane >> 4, l15 = lane & 15;

  const char* aSrcBase = aimg + (size_t)tile * NKT * TILE_B;
  // A: wave w owns plane w, 5 row-group chunks of 1KB
  const char* srcA[5];
  int dstA[5];
  #pragma unroll
  for (int j = 0; j < 5; ++j) {
    srcA[j] = aSrcBase + wid * PLANE_B + j * 1024 + lane * 16;
    dstA[j] = wid * PLANE_B + j * 1024;
  }
  // B: BCH chunks of 1KB (4 cols x 256B), BCH/8 per wave; bank-swizzle in SOURCE addr
  const char* srcB[BCH / 8];
  int dstB[BCH / 8];
  #pragma unroll
  for (int j = 0; j < BCH / 8; ++j) {
    int cb = wid * (BCH / 8) + j;
    int col = nt * BN_ + cb * 4 + (lane >> 4);
    int s16 = lane & 15;
    int swz = (((s16 >> 1) ^ (col & 7)) << 5) | ((s16 & 1) << 4);
    srcB[j] = (const char*)wgt + ((size_t)(e * NCOLS_TOT + col) * HIDDEN) * 4 + swz;
    dstB[j] = cb * 1024;
  }

  auto STAGE = [&](int kt, int buf) {
    #pragma unroll
    for (int j = 0; j < 5; ++j)
      gl2lds(srcA[j] + (size_t)kt * TILE_B, lds + buf * ABUF + dstA[j]);
    #pragma unroll
    for (int j = 0; j < BCH / 8; ++j)
      gl2lds(srcB[j] + (size_t)kt * 256, ldsB + buf * BBUF + dstB[j]);
  };

  f32x4 acc[5][FN];
  #pragma unroll
  for (int fm = 0; fm < 5; ++fm)
    #pragma unroll
    for (int fn = 0; fn < FN; ++fn)
      acc[fm][fn] = f32x4{0.f, 0.f, 0.f, 0.f};

  auto COMP = [&](int buf) {
    const char* aT = lds + buf * ABUF;
    const char* bT = ldsB + buf * BBUF;
    #pragma unroll
    for (int s = 0; s < 2; ++s) {
      const char* aB = aT + (s * 4 + kq) * PLANE_B + (wm * 80 + l15) * 16;
      bf16x8 af[5], bf[FN];
      #pragma unroll
      for (int fm = 0; fm < 5; ++fm) af[fm] = *(const bf16x8*)(aB + fm * 256);
      #pragma unroll
      for (int fn = 0; fn < FN; ++fn) {
        int col = wn * (BN_ / 2) + fn * 16 + l15;
        int slot = ((s * 4 + kq) ^ (col & 7)) << 5;
        const char* cp = bT + col * 256 + slot;
        float4 lo = *(const float4*)cp;
        float4 hi = *(const float4*)(cp + 16);
        bf[fn] = cvt8(lo, hi);
      }
      #pragma unroll
      for (int fm = 0; fm < 5; ++fm)
        #pragma unroll
        for (int fn = 0; fn < FN; ++fn)
          acc[fm][fn] = __builtin_amdgcn_mfma_f32_16x16x32_bf16(af[fm], bf[fn], acc[fm][fn], 0, 0, 0);
    }
  };

  STAGE(0, 0);
  for (int kt = 0; kt < NKT; ++kt) {
    if (kt + 1 < NKT) {
      STAGE(kt + 1, (kt + 1) & 1);
      if constexpr (BN_ == 160) { WAITVM(10) } else { WAITVM(8) }
    } else { WAITVM(0) }
    barrier();
    COMP(kt & 1);
    barrier();
  }

  if (SWIGLU) {
    #pragma unroll
    for (int fm = 0; fm < 5; ++fm) {
      #pragma unroll
      for (int fn = 0; fn < FN; ++fn) {
        const int colg = nt * BN_ + wn * (BN_ / 2) + fn * 16 + l15;
        const float bias = wbias[e * NCOLS_TOT + colg];
        #pragma unroll
        for (int j = 0; j < 4; ++j) {
          float h = acc[fm][fn][j] + bias;
          float other = __shfl_xor(h, 1, 64);
          int rowin = wm * 80 + fm * 16 + kq * 4 + j;
          if (!(lane & 1) && rowin < rows) {
            float xg = fminf(h, 7.0f);
            float xl = fminf(fmaxf(other, -7.0f), 7.0f);
            float og = xg / (1.0f + __expf(-1.702f * xg));
            float uv = og * (xl + 1.0f);
            int uc = colg >> 1;                      // 0..2879
            int kt2 = uc >> 6, p2 = (uc >> 3) & 7;
            *(__hip_bfloat16*)(uimg + (size_t)(tile * NKT + kt2) * TILE_B +
                p2 * PLANE_B + rowin * 16 + (uc & 7) * 2) = __float2bfloat16(uv);
          }
        }
      }
    }
  } else {
    const int base = meta[8 + e];
    #pragma unroll
    for (int fm = 0; fm < 5; ++fm) {
      #pragma unroll
      for (int j = 0; j < 4; ++j) {
        int rin = wm * 80 + fm * 16 + kq * 4 + j;
        int aidx = (rin < rows) ? list[base + m0 + rin] : -1;
        #pragma unroll
        for (int fn = 0; fn < FN; ++fn) {
          int col = nt * BN_ + wn * (BN_ / 2) + fn * 16 + l15;
          if (aidx >= 0)
            out[(size_t)aidx * HIDDEN + col] = acc[fm][fn][j] + wbias[e * NCOLS_TOT + col];
        }
      }
    }
  }
}

extern "C" void kernel_launch(void* const* d_in, const int* in_sizes, int n_in,
                              void* d_out, int out_size, void* d_ws, size_t ws_size,
                              hipStream_t stream) {
  const float* t     = (const float*)d_in[0];
  const int*   eidx  = (const int*)d_in[1];
  const float* gup   = (const float*)d_in[2];
  const float* gub   = (const float*)d_in[3];
  const float* dwn   = (const float*)d_in[4];
  const float* dbias = (const float*)d_in[5];
  float* out = (float*)d_out;

  char* ws = (char*)d_ws;
  char* atile = ws;
  char* utile = ws + IMG_BYTES;
  int* meta = (int*)(ws + 2 * IMG_BYTES);
  int* list = meta + 32;

  route_count<<<1, 256, 0, stream>>>(eidx, meta);
  route_scatter<<<NPAIR / 256, 256, 0, stream>>>(eidx, meta, list);
  gather_a<<<NPAIR, 256, 0, stream>>>(t, eidx, meta, list, atile);

  dim3 g1(NEXP, GUP_ROWS / 160, 2);   // 8 x 36 x 2 (mt=1 safety tier, normally exits)
  gemm_core<160, GUP_ROWS, true><<<g1, 512, 0, stream>>>(atile, gup, gub, meta, list, utile, out);

  dim3 g2(NEXP, HIDDEN / 96, 2);      // 8 x 30 x 2
  gemm_core<96, HIDDEN, false><<<g2, 512, 0, stream>>>(utile, dwn, dbias, meta, list, nullptr, out);
}

// Round 14
// 298.303 us; speedup vs baseline: 1.4834x; 1.3326x over previous
//
#include <hip/hip_runtime.h>
#include <hip/hip_bf16.h>

#define HIDDEN   2880
#define INTER    2880
#define NEXP     8
#define GUP_ROWS 5760
#define NPAIR    2048

#define BM    320
#define PLANE_B 5120         // one 8-k plane: 320 rows x 16B
#define KT64_B  40960        // BK=64 tile: 8 planes
#define NKT64   45
#define KT32_B  20480        // BK=32 tile: 4 planes
#define NKT32   90

#define MAXTILES 15
#define IMG_BYTES ((size_t)MAXTILES * NKT64 * KT64_B)

using bf16x8 = __attribute__((ext_vector_type(8))) short;
using f32x4  = __attribute__((ext_vector_type(4))) float;

typedef const __attribute__((address_space(1))) unsigned GBuf;
typedef __attribute__((address_space(3))) unsigned LBuf;

__device__ __forceinline__ void gl2lds(const void* g, void* l) {
  __builtin_amdgcn_global_load_lds((GBuf*)g, (LBuf*)l, 16, 0, 0);
}
#define WAITVM(N) { asm volatile("s_waitcnt vmcnt(" #N ")" ::: "memory"); \
                    __builtin_amdgcn_sched_barrier(0); }
__device__ __forceinline__ void barrier() {
  __builtin_amdgcn_sched_barrier(0);
  __builtin_amdgcn_s_barrier();
  __builtin_amdgcn_sched_barrier(0);
}

__device__ __forceinline__ unsigned cvt2bf(float a, float b) {
  union { __hip_bfloat16 h; unsigned short s; } x, y;
  x.h = __float2bfloat16(a);
  y.h = __float2bfloat16(b);
  return (unsigned)x.s | ((unsigned)y.s << 16);
}
__device__ __forceinline__ bf16x8 cvt8(const float4& lo, const float4& hi) {
  union { bf16x8 v; unsigned u[4]; } r;
  r.u[0] = cvt2bf(lo.x, lo.y);
  r.u[1] = cvt2bf(lo.z, lo.w);
  r.u[2] = cvt2bf(hi.x, hi.y);
  r.u[3] = cvt2bf(hi.z, hi.w);
  return r.v;
}

// ---------------- routing ----------------
__global__ void route_count(const int* __restrict__ eidx, int* __restrict__ meta) {
  __shared__ int cnt[NEXP];
  int t = threadIdx.x;
  if (t < NEXP) cnt[t] = 0;
  __syncthreads();
  for (int a = t; a < NPAIR; a += 256) atomicAdd(&cnt[eidx[a]], 1);
  __syncthreads();
  if (t == 0) {
    int off = 0, toff = 0;
    for (int e = 0; e < NEXP; ++e) {
      meta[e] = cnt[e];
      meta[8 + e] = off;
      meta[16 + e] = off;
      meta[24 + e] = toff;
      off += cnt[e];
      toff += (cnt[e] + BM - 1) / BM;
    }
  }
}

__global__ void route_scatter(const int* __restrict__ eidx, int* __restrict__ meta,
                              int* __restrict__ list) {
  int a = blockIdx.x * 256 + threadIdx.x;
  int e = eidx[a];
  int pos = atomicAdd(&meta[16 + e], 1);
  list[pos] = a;
}

// ---------------- gather A rows -> bf16 tiled fragment image ----------------
// layout: [tile][k>>3 plane 0..359][row 0..319][16B]  (same bytes for BK=32/64 views)
__global__ void gather_a(const float* __restrict__ t, const int* __restrict__ eidx,
                         const int* __restrict__ meta, const int* __restrict__ list,
                         char* __restrict__ atile) {
  const int i = blockIdx.x;
  const int a = list[i];
  const int e = eidx[a];
  const int r = i - meta[8 + e];
  const int tile = meta[24 + e] + r / BM;
  const int row = r % BM;
  const float* src = t + (size_t)(a >> 2) * HIDDEN;
  for (int ch = threadIdx.x; ch < HIDDEN / 8; ch += 256) {
    const float4* s = (const float4*)(src + ch * 8);
    float4 v0 = s[0], v1 = s[1];
    uint4 w;
    w.x = cvt2bf(v0.x, v0.y); w.y = cvt2bf(v0.z, v0.w);
    w.z = cvt2bf(v1.x, v1.y); w.w = cvt2bf(v1.z, v1.w);
    *(uint4*)(atile + ((size_t)tile * 360 + ch) * PLANE_B + row * 16) = w;
  }
}

// ---------------- GEMM1: 4 waves (4 wm), tile 320x96, BK=32, 64KB LDS -> 2 blocks/CU ----------------
// 32 chunks/iter (20 A + 12 B), 8 gl2lds/wave -> WAITVM(8).
__global__ __launch_bounds__(256, 2)
void gemm1_swiglu(const char* __restrict__ aimg,
                  const float* __restrict__ gup,
                  const float* __restrict__ gub,
                  const int* __restrict__ meta,
                  char* __restrict__ uimg)
{
  const int e = blockIdx.x, nt = blockIdx.y, mt = blockIdx.z;
  const int n_e = meta[e];
  const int m0 = mt * BM;
  if (m0 >= n_e) return;
  const int tile = meta[24 + e] + mt;
  int rows = n_e - m0; if (rows > BM) rows = BM;

  __shared__ __align__(16) char lds[2 * 32768];   // 64 KB

  const int tid = threadIdx.x, lane = tid & 63, wid = tid >> 6;
  const int wm = wid;
  const int kq = lane >> 4, l15 = lane & 15;

  const char* aSrc = aimg + (size_t)tile * 360 * PLANE_B;
  // A: 20 chunks of 1KB, 5 per wave
  const char* srcA[5]; int dstA[5];
  #pragma unroll
  for (int j = 0; j < 5; ++j) {
    int c = wid * 5 + j;
    srcA[j] = aSrc + c * 1024 + lane * 16;
    dstA[j] = c * 1024;
  }
  // B: 12 chunks of 1KB (8 cols x 128B), 3 per wave; swizzle in SOURCE addr
  const char* srcB[3]; int dstB[3];
  #pragma unroll
  for (int j = 0; j < 3; ++j) {
    int cb = wid * 3 + j;
    int col = nt * 96 + cb * 8 + (lane >> 3);
    int g = (lane & 7) >> 1, h = lane & 1;
    srcB[j] = (const char*)gup + (size_t)(e * GUP_ROWS + col) * (HIDDEN * 4)
              + (((g ^ (col & 3)) << 5) | (h << 4));
    dstB[j] = 20480 + cb * 1024;
  }

  auto STAGE = [&](int kt, int buf) {
    char* dst = lds + buf * 32768;
    #pragma unroll
    for (int j = 0; j < 5; ++j)
      gl2lds(srcA[j] + (size_t)kt * KT32_B, dst + dstA[j]);
    #pragma unroll
    for (int j = 0; j < 3; ++j)
      gl2lds(srcB[j] + (size_t)kt * 128, dst + dstB[j]);
  };

  f32x4 acc[5][6];
  #pragma unroll
  for (int fm = 0; fm < 5; ++fm)
    #pragma unroll
    for (int fn = 0; fn < 6; ++fn)
      acc[fm][fn] = f32x4{0.f, 0.f, 0.f, 0.f};

  auto COMP = [&](int buf) {
    const char* base = lds + buf * 32768;
    const char* aB = base + kq * PLANE_B + (wm * 80 + l15) * 16;
    bf16x8 af[5], bf[6];
    #pragma unroll
    for (int fm = 0; fm < 5; ++fm) af[fm] = *(const bf16x8*)(aB + fm * 256);
    #pragma unroll
    for (int fn = 0; fn < 6; ++fn) {
      int col = fn * 16 + l15;
      const char* cp = base + 20480 + col * 128 + ((kq ^ (col & 3)) << 5);
      float4 lo = *(const float4*)cp;
      float4 hi = *(const float4*)(cp + 16);
      bf[fn] = cvt8(lo, hi);
    }
    #pragma unroll
    for (int fm = 0; fm < 5; ++fm)
      #pragma unroll
      for (int fn = 0; fn < 6; ++fn)
        acc[fm][fn] = __builtin_amdgcn_mfma_f32_16x16x32_bf16(af[fm], bf[fn], acc[fm][fn], 0, 0, 0);
  };

  STAGE(0, 0);
  for (int kt = 0; kt < NKT32; ++kt) {
    if (kt + 1 < NKT32) {
      STAGE(kt + 1, (kt + 1) & 1);
      WAITVM(8)
    } else { WAITVM(0) }
    barrier();
    COMP(kt & 1);
    barrier();
  }

  // epilogue: +bias, swiglu (even col = glu, odd = lin), write u into uimg
  #pragma unroll
  for (int fm = 0; fm < 5; ++fm) {
    #pragma unroll
    for (int fn = 0; fn < 6; ++fn) {
      const int colg = nt * 96 + fn * 16 + l15;
      const float bias = gub[e * GUP_ROWS + colg];
      #pragma unroll
      for (int j = 0; j < 4; ++j) {
        float h = acc[fm][fn][j] + bias;
        float other = __shfl_xor(h, 1, 64);
        int rowin = wm * 80 + fm * 16 + kq * 4 + j;
        if (!(lane & 1) && rowin < rows) {
          float xg = fminf(h, 7.0f);
          float xl = fminf(fmaxf(other, -7.0f), 7.0f);
          float og = xg / (1.0f + __expf(-1.702f * xg));
          float uv = og * (xl + 1.0f);
          int uc = colg >> 1;                      // 0..2879
          *(__hip_bfloat16*)(uimg + ((size_t)tile * 360 + (uc >> 3)) * PLANE_B +
              rowin * 16 + (uc & 7) * 2) = __float2bfloat16(uv);
        }
      }
    }
  }
}

// ---------------- GEMM2: 8 waves (4 wm x 2 wn), tile 320x96, BK=64 (proven R13 config) ----------------
__global__ __launch_bounds__(512, 1)
void gemm2_down(const char* __restrict__ uimg,
                const float* __restrict__ dwn,
                const float* __restrict__ dbias,
                const int* __restrict__ meta,
                const int* __restrict__ list,
                float* __restrict__ out)
{
  constexpr int BN_ = 96;
  constexpr int BBUF = BN_ * 256;       // 24576

  const int e = blockIdx.x, nt = blockIdx.y, mt = blockIdx.z;
  const int n_e = meta[e];
  const int m0 = mt * BM;
  if (m0 >= n_e) return;
  const int tile = meta[24 + e] + mt;
  int rows = n_e - m0; if (rows > BM) rows = BM;

  __shared__ __align__(16) char lds[2 * KT64_B + 2 * BBUF];   // 128 KB
  char* ldsB = lds + 2 * KT64_B;

  const int tid = threadIdx.x, lane = tid & 63, wid = tid >> 6;
  const int wm = wid >> 1, wn = wid & 1;
  const int kq = lane >> 4, l15 = lane & 15;

  const char* aSrcBase = uimg + (size_t)tile * 360 * PLANE_B;
  const char* srcA[5]; int dstA[5];
  #pragma unroll
  for (int j = 0; j < 5; ++j) {
    srcA[j] = aSrcBase + wid * PLANE_B + j * 1024 + lane * 16;
    dstA[j] = wid * PLANE_B + j * 1024;
  }
  const char* srcB[3]; int dstB[3];
  #pragma unroll
  for (int j = 0; j < 3; ++j) {
    int cb = wid * 3 + j;
    int col = nt * BN_ + cb * 4 + (lane >> 4);
    int s16 = lane & 15;
    int swz = (((s16 >> 1) ^ (col & 7)) << 5) | ((s16 & 1) << 4);
    srcB[j] = (const char*)dwn + ((size_t)(e * HIDDEN + col) * INTER) * 4 + swz;
    dstB[j] = cb * 1024;
  }

  auto STAGE = [&](int kt, int buf) {
    #pragma unroll
    for (int j = 0; j < 5; ++j)
      gl2lds(srcA[j] + (size_t)kt * KT64_B, lds + buf * KT64_B + dstA[j]);
    #pragma unroll
    for (int j = 0; j < 3; ++j)
      gl2lds(srcB[j] + (size_t)kt * 256, ldsB + buf * BBUF + dstB[j]);
  };

  f32x4 acc[5][3];
  #pragma unroll
  for (int fm = 0; fm < 5; ++fm)
    #pragma unroll
    for (int fn = 0; fn < 3; ++fn)
      acc[fm][fn] = f32x4{0.f, 0.f, 0.f, 0.f};

  auto COMP = [&](int buf) {
    const char* aT = lds + buf * KT64_B;
    const char* bT = ldsB + buf * BBUF;
    #pragma unroll
    for (int s = 0; s < 2; ++s) {
      const char* aB = aT + (s * 4 + kq) * PLANE_B + (wm * 80 + l15) * 16;
      bf16x8 af[5], bf[3];
      #pragma unroll
      for (int fm = 0; fm < 5; ++fm) af[fm] = *(const bf16x8*)(aB + fm * 256);
      #pragma unroll
      for (int fn = 0; fn < 3; ++fn) {
        int col = wn * 48 + fn * 16 + l15;
        int slot = ((s * 4 + kq) ^ (col & 7)) << 5;
        const char* cp = bT + col * 256 + slot;
        float4 lo = *(const float4*)cp;
        float4 hi = *(const float4*)(cp + 16);
        bf[fn] = cvt8(lo, hi);
      }
      #pragma unroll
      for (int fm = 0; fm < 5; ++fm)
        #pragma unroll
        for (int fn = 0; fn < 3; ++fn)
          acc[fm][fn] = __builtin_amdgcn_mfma_f32_16x16x32_bf16(af[fm], bf[fn], acc[fm][fn], 0, 0, 0);
    }
  };

  STAGE(0, 0);
  for (int kt = 0; kt < NKT64; ++kt) {
    if (kt + 1 < NKT64) {
      STAGE(kt + 1, (kt + 1) & 1);
      WAITVM(8)
    } else { WAITVM(0) }
    barrier();
    COMP(kt & 1);
    barrier();
  }

  const int base = meta[8 + e];
  #pragma unroll
  for (int fm = 0; fm < 5; ++fm) {
    #pragma unroll
    for (int j = 0; j < 4; ++j) {
      int rin = wm * 80 + fm * 16 + kq * 4 + j;
      int aidx = (rin < rows) ? list[base + m0 + rin] : -1;
      #pragma unroll
      for (int fn = 0; fn < 3; ++fn) {
        int col = nt * BN_ + wn * 48 + fn * 16 + l15;
        if (aidx >= 0)
          out[(size_t)aidx * HIDDEN + col] = acc[fm][fn][j] + dbias[e * HIDDEN + col];
      }
    }
  }
}

extern "C" void kernel_launch(void* const* d_in, const int* in_sizes, int n_in,
                              void* d_out, int out_size, void* d_ws, size_t ws_size,
                              hipStream_t stream) {
  const float* t     = (const float*)d_in[0];
  const int*   eidx  = (const int*)d_in[1];
  const float* gup   = (const float*)d_in[2];
  const float* gub   = (const float*)d_in[3];
  const float* dwn   = (const float*)d_in[4];
  const float* dbias = (const float*)d_in[5];
  float* out = (float*)d_out;

  char* ws = (char*)d_ws;
  char* atile = ws;
  char* utile = ws + IMG_BYTES;
  int* meta = (int*)(ws + 2 * IMG_BYTES);
  int* list = meta + 32;

  route_count<<<1, 256, 0, stream>>>(eidx, meta);
  route_scatter<<<NPAIR / 256, 256, 0, stream>>>(eidx, meta, list);
  gather_a<<<NPAIR, 256, 0, stream>>>(t, eidx, meta, list, atile);

  dim3 g1(NEXP, GUP_ROWS / 96, 2);    // 8 x 60 x 2 (mt=1 safety tier, normally exits)
  gemm1_swiglu<<<g1, 256, 0, stream>>>(atile, gup, gub, meta, utile);

  dim3 g2(NEXP, HIDDEN / 96, 2);      // 8 x 30 x 2
  gemm2_down<<<g2, 512, 0, stream>>>(utile, dwn, dbias, meta, list, out);
}